// Round 5
// baseline (1275.102 us; speedup 1.0000x reference)
//
#include <hip/hip_runtime.h>

#define TOK   8192
#define DD    1024
#define FF    4096
#define EE    8
#define TWOF  8192
#define NSLOT 16384   // TOK * top_k(2)

typedef unsigned short u16;
typedef float  f32x4  __attribute__((ext_vector_type(4)));
typedef __bf16 bf16x8 __attribute__((ext_vector_type(8)));

__device__ __forceinline__ u16 f2b(float f) {
  unsigned u = __builtin_bit_cast(unsigned, f);
  u += 0x7fffu + ((u >> 16) & 1u);   // RNE; inputs finite
  return (u16)(u >> 16);
}

__device__ __forceinline__ void ldslds16(const void* g, void* l) {
  __builtin_amdgcn_global_load_lds((const __attribute__((address_space(1))) void*)g,
                                   (__attribute__((address_space(3))) void*)l, 16, 0, 0);
}

__device__ __forceinline__ long long llmin(long long a, long long b) { return a < b ? a : b; }

// ---------------- gate: logits, softmax, top-2, counts ----------------
__global__ void gate_kernel(const float* __restrict__ x, const float* __restrict__ gw,
                            const float* __restrict__ gb, int* __restrict__ counts,
                            int* __restrict__ eidx, int* __restrict__ epos,
                            float* __restrict__ ew) {
  const int wave = threadIdx.x >> 6, lane = threadIdx.x & 63;
  const int t = blockIdx.x * 4 + wave;
  float acc[EE] = {0,0,0,0,0,0,0,0};
  const float* xr = x + (size_t)t * DD;
  for (int d = lane; d < DD; d += 64) {
    float xv = xr[d];
    const float* g = gw + (size_t)d * EE;
#pragma unroll
    for (int e = 0; e < EE; ++e) acc[e] += xv * g[e];
  }
#pragma unroll
  for (int e = 0; e < EE; ++e)
#pragma unroll
    for (int off = 32; off > 0; off >>= 1) acc[e] += __shfl_down(acc[e], off);
  if (lane == 0) {
    float l[EE];
#pragma unroll
    for (int e = 0; e < EE; ++e) l[e] = acc[e] + gb[e];
    int i0 = 0;
    for (int e = 1; e < EE; ++e) if (l[e] > l[i0]) i0 = e;
    int i1 = (i0 == 0) ? 1 : 0;
    for (int e = 0; e < EE; ++e) { if (e == i0) continue; if (l[e] > l[i1]) i1 = e; }
    float m = l[0];
    for (int e = 1; e < EE; ++e) m = fmaxf(m, l[e]);
    float s = 0.f, p[EE];
    for (int e = 0; e < EE; ++e) { p[e] = __expf(l[e] - m); s += p[e]; }
    float w0 = p[i0] / s, w1 = p[i1] / s;
    int p0 = atomicAdd(&counts[i0], 1);
    int p1 = atomicAdd(&counts[i1], 1);
    eidx[2*t] = i0; eidx[2*t+1] = i1;
    epos[2*t] = p0; epos[2*t+1] = p1;
    ew[2*t] = w0;  ew[2*t+1] = w1;
  }
}

// slot: inline-scans counts (8 ints, L2-hot)
__global__ void slot_kernel(const int* __restrict__ eidx, const int* __restrict__ epos,
                            const float* __restrict__ ew, const int* __restrict__ counts,
                            int* __restrict__ s2t, float* __restrict__ swt,
                            int* __restrict__ t2s) {
  int i = blockIdx.x * 256 + threadIdx.x;           // 0..2T-1
  int e = eidx[i];
  int off = 0;
  for (int j = 0; j < e; ++j) off += counts[j];
  int slot = off + epos[i];
  s2t[slot] = i >> 1;
  swt[slot] = ew[i];
  t2s[i] = slot;
}

// ---------------- conversions ----------------
__global__ void cvtx_kernel(const float* __restrict__ x, u16* __restrict__ xb) {
  int i = blockIdx.x * 256 + threadIdx.x;           // 4 elements each
  float4 v = ((const float4*)x)[i];
  unsigned lo = (unsigned)f2b(v.x) | ((unsigned)f2b(v.y) << 16);
  unsigned hi = (unsigned)f2b(v.z) | ((unsigned)f2b(v.w) << 16);
  ((uint2*)xb)[i] = make_uint2(lo, hi);
}

__global__ void gather_kernel(const u16* __restrict__ xb, const int* __restrict__ s2t,
                              u16* __restrict__ xg) {
  int i = blockIdx.x * 256 + threadIdx.x;           // 16B chunks
  int row = i >> 7, c = i & 127;
  int tok = s2t[row];
  ((int4*)xg)[(size_t)row * 128 + c] = ((const int4*)xb)[(size_t)tok * 128 + c];
}

// transpose-convert weights: dst[seg][n][k] (bf16) = src[seg][k][oc(n)] (f32)
// permute (w1 only): interleave a/b halves in 16-col groups (SwiGLU pairing, 16x16 frags)
__global__ void wt_kernel(const float* __restrict__ srcS, const float* __restrict__ srcR,
                          u16* __restrict__ dst, int K, int N, int permute) {
  __shared__ float tile[32][33];
  const int seg = blockIdx.z;
  const float* src = (seg == 0) ? srcS : srcR + (size_t)(seg - 1) * K * N;
  const int pc0 = blockIdx.x * 32, k0 = blockIdx.y * 32;
  const int tid = threadIdx.x;
  {
    int kk = tid >> 3, j4 = (tid & 7) << 2;
    const float* srow = src + (size_t)(k0 + kk) * N;
#pragma unroll
    for (int q = 0; q < 4; ++q) {
      int n = pc0 + j4 + q;
      int oc = permute ? (((n >> 5) << 4) + (n & 15) + ((n & 16) ? FF : 0)) : n;
      tile[kk][j4 + q] = srow[oc];
    }
  }
  __syncthreads();
  {
    int pp = tid >> 3, kq = (tid & 7) << 2;
    u16* drow = dst + (size_t)seg * N * K + (size_t)(pc0 + pp) * K + k0 + kq;
#pragma unroll
    for (int q = 0; q < 4; ++q) drow[q] = f2b(tile[kq + q][pp]);
  }
}

// ================= 256x256x64 pipelined GEMM core =================
// 512 threads = 8 waves (2M x 4N); per-wave 128x64 out = acc[8][4] 16x16 frags.
// LDS 128 KiB: A[2dbuf][2half][128][64]bf16 @0, B same @65536.
// 4 phases/K-tile: reads one phase AHEAD (cross-phase pipeline), 16 MFMA/phase,
// stage tile t+1 (8 gloads) at p0/p1, single vmcnt(0)+barrier boundary at p3.

#define MFMA16(MS, AF, BQ) \
  _Pragma("unroll") for (int mi = 0; mi < 4; ++mi) \
  _Pragma("unroll") for (int ni = 0; ni < 4; ++ni) \
    acc[(MS)*4+mi][ni] = __builtin_amdgcn_mfma_f32_16x16x32_bf16(AF[mi], BQ[ni], acc[(MS)*4+mi][ni], 0, 0, 0);

#define LDA4(DST, MS, KK, D) \
  _Pragma("unroll") for (int i = 0; i < 4; ++i) \
    DST[i] = *(const bf16x8*)(lds + (D)*32768 + afbase[(MS)*4+i] + kcol[KK]);

#define LDB4(DST, KK, D) \
  _Pragma("unroll") for (int i = 0; i < 4; ++i) \
    DST[i] = *(const bf16x8*)(lds + (D)*32768 + bqbase[i] + kcol[KK]);

#define STAGE_A(DN, KOFF) \
  _Pragma("unroll") for (int s = 0; s < 4; ++s) \
    ldslds16(gsA[s] + (KOFF), lds + (DN)*32768 + s*8192 + tid*16);

#define STAGE_B(DN, KOFF) \
  _Pragma("unroll") for (int s = 0; s < 4; ++s) \
    ldslds16(gsB[s] + (KOFF), lds + 65536 + (DN)*32768 + s*8192 + tid*16);

#define BAR()   __builtin_amdgcn_s_barrier()
#define VMC0()  asm volatile("s_waitcnt vmcnt(0)" ::: "memory")
#define PRIO(v) __builtin_amdgcn_s_setprio(v)

template<int NT>
__device__ __forceinline__ void gemm_core(
    const char* Aseg, long long lda, long long arow0, long long armax,
    const char* Bseg, long long ldb, long long bcol0,
    char* lds, int tid, f32x4 (&acc)[8][4]) {
  const int lane = tid & 63, wid = tid >> 6;
  const int wm = wid >> 2, wn = wid & 3;
  const int fr = lane & 15;
  const int swz = (fr & 7) << 4;
  int kcol[2];
  kcol[0] = ((lane >> 4) * 16) ^ swz;
  kcol[1] = (64 + (lane >> 4) * 16) ^ swz;
  int afbase[8], bqbase[4];
#pragma unroll
  for (int mf = 0; mf < 8; ++mf) afbase[mf] = wm * 16384 + (mf * 16 + fr) * 128;
#pragma unroll
  for (int nf = 0; nf < 4; ++nf)
    bqbase[nf] = 65536 + (wn >> 1) * 16384 + ((wn & 1) * 64 + nf * 16 + fr) * 128;

  // staging source pointers (per-thread, pre-swizzled cols)
  const int srow = tid >> 3, schunk = (tid & 7) * 16;
  const char* gsA[4]; const char* gsB[4];
#pragma unroll
  for (int s = 0; s < 4; ++s) {
    int rloc = s * 64 + srow;                        // s = h*2+g, rows h*128+g*64+srow
    long long rg = llmin(arow0 + rloc, armax);
    gsA[s] = Aseg + rg * lda + (schunk ^ ((rloc & 7) << 4));
    gsB[s] = Bseg + (bcol0 + rloc) * ldb + (schunk ^ ((rloc & 7) << 4));
  }

  bf16x8 af0[4], af1[4], bq0[4], bq1[4];

  // prologue: stage tile 0 into dbuf 0
  STAGE_A(0, 0); STAGE_B(0, 0);
  VMC0(); BAR();
  LDA4(af0, 0, 0, 0); LDB4(bq0, 0, 0);

  for (int t = 0; t < NT; ++t) {
    const int d = t & 1, dn = d ^ 1;
    const bool more = (t + 1) < NT;
    const long long koff = (long long)(t + 1) * 128;

    // p0: MFMA m0-3 kk0; prefetch af(m4-7,kk0); stage A(t+1)
    LDA4(af1, 1, 0, d);
    if (more) { STAGE_A(dn, koff); }
    BAR(); PRIO(1); MFMA16(0, af0, bq0); PRIO(0); BAR();

    // p1: MFMA m4-7 kk0; prefetch af(m0-3,kk1)+bq(kk1); stage B(t+1)
    LDA4(af0, 0, 1, d); LDB4(bq1, 1, d);
    if (more) { STAGE_B(dn, koff); }
    BAR(); PRIO(1); MFMA16(1, af1, bq0); PRIO(0); BAR();

    // p2: MFMA m0-3 kk1; prefetch af(m4-7,kk1)
    LDA4(af1, 1, 1, d);
    BAR(); PRIO(1); MFMA16(0, af0, bq1); PRIO(0); BAR();

    // p3: tile boundary — stages of t+1 landed (own wave) then barrier (all waves);
    //     next-tile reads issued AFTER barrier, overlap this phase's MFMA
    if (more) { VMC0(); }
    BAR();
    if (more) { LDA4(af0, 0, 0, dn); LDB4(bq0, 0, dn); }
    PRIO(1); MFMA16(1, af1, bq1); PRIO(0); BAR();
  }
}

// ---------------- GEMM1: x @ w1t(permuted) -> SwiGLU -> hs bf16 ----------------
__global__ __launch_bounds__(512, 2)
void gemm1_kernel(const u16* __restrict__ xb, const u16* __restrict__ xg,
                  const u16* __restrict__ w1t, const float* __restrict__ sb1,
                  const float* __restrict__ rb1, const int* __restrict__ counts,
                  u16* __restrict__ hs) {
  __shared__ __align__(16) char lds[131072];
  const int seg = blockIdx.z;
  int rowstart, rows, hsbase, atot;
  const u16* A;
  if (seg == 0) { A = xb; rowstart = 0; rows = TOK; hsbase = 0; atot = TOK; }
  else {
    int o0 = 0;
    for (int j = 0; j < seg - 1; ++j) o0 += counts[j];
    A = xg; rowstart = o0; rows = counts[seg - 1]; hsbase = TOK + o0; atot = NSLOT;
  }
  const int tm = blockIdx.y;
  if (tm * 256 >= rows) return;
  const int tn = blockIdx.x;
  const int tid = threadIdx.x, lane = tid & 63, wid = tid >> 6;
  const int wm = wid >> 2, wn = wid & 3;

  f32x4 acc[8][4] = {};
  gemm_core<DD / 64>((const char*)A, DD * 2, rowstart + tm * 256, atot - 1,
                     (const char*)(w1t + (size_t)seg * TWOF * DD), DD * 2, tn * 256,
                     lds, tid, acc);

  const int fr = lane & 15, lq = lane >> 4;
  const int rlim = rows - tm * 256;
  const float* b1 = (seg == 0) ? sb1 : rb1 + (size_t)(seg - 1) * TWOF;
  u16* hbase = hs + (size_t)(hsbase + tm * 256) * FF;
#pragma unroll
  for (int u = 0; u < 2; ++u) {
    const int pc = (tn * 8 + wn * 2 + u) * 16 + fr;
    const float ba = b1[pc], bb = b1[FF + pc];
#pragma unroll
    for (int mf = 0; mf < 8; ++mf)
#pragma unroll
      for (int q = 0; q < 4; ++q) {
        int lr = wm * 128 + mf * 16 + lq * 4 + q;
        if (lr < rlim) {
          float av = acc[mf][2*u][q] + ba;
          float bv = acc[mf][2*u+1][q] + bb;
          float sv = av / (1.0f + __expf(-av)) * bv;
          hbase[(size_t)lr * FF + pc] = f2b(sv);
        }
      }
  }
}

// ---------------- GEMM2: hs @ w2t -> yo (f32, all segments, no atomics) ----------------
__global__ __launch_bounds__(512, 2)
void gemm2_kernel(const u16* __restrict__ hs, const u16* __restrict__ w2t,
                  const float* __restrict__ sb2, const float* __restrict__ rb2,
                  const int* __restrict__ counts, float* __restrict__ yo) {
  __shared__ __align__(16) char lds[131072];
  const int seg = blockIdx.z;
  int rows, hrow0;
  if (seg == 0) { rows = TOK; hrow0 = 0; }
  else {
    int o0 = 0;
    for (int j = 0; j < seg - 1; ++j) o0 += counts[j];
    rows = counts[seg - 1]; hrow0 = TOK + o0;
  }
  const int tm = blockIdx.y;
  if (tm * 256 >= rows) return;
  const int tn = blockIdx.x;
  const int tid = threadIdx.x, lane = tid & 63, wid = tid >> 6;
  const int wm = wid >> 2, wn = wid & 3;

  f32x4 acc[8][4] = {};
  gemm_core<FF / 64>((const char*)hs, FF * 2, hrow0 + tm * 256, TOK + NSLOT + 255,
                     (const char*)(w2t + (size_t)seg * DD * FF), FF * 2, tn * 256,
                     lds, tid, acc);

  const int fr = lane & 15, lq = lane >> 4;
  const int rlim = rows - tm * 256;
  const float* b2 = (seg == 0) ? sb2 : rb2 + (size_t)(seg - 1) * DD;
  float* ybase = yo + (size_t)(hrow0 + tm * 256) * DD;
#pragma unroll
  for (int nf = 0; nf < 4; ++nf) {
    const int c = tn * 256 + wn * 64 + nf * 16 + fr;
    const float bias = b2[c];
#pragma unroll
    for (int mf = 0; mf < 8; ++mf)
#pragma unroll
      for (int q = 0; q < 4; ++q) {
        int lr = wm * 128 + mf * 16 + lq * 4 + q;
        if (lr < rlim) ybase[(size_t)lr * DD + c] = acc[mf][nf][q] + bias;
      }
  }
}

// ---------------- combine: out[t] = yo[t] + w0*yo[T+s0] + w1*yo[T+s1] ----------------
__global__ void combine_kernel(const float* __restrict__ yo, const int* __restrict__ t2s,
                               const float* __restrict__ ew, float* __restrict__ out) {
  const int t = blockIdx.x, d = threadIdx.x;   // 256 threads x 4 floats
  const float4 a  = ((const float4*)(yo + (size_t)t * DD))[d];
  const int s0 = t2s[2*t], s1 = t2s[2*t+1];
  const float w0 = ew[2*t], w1 = ew[2*t+1];
  const float4 r0 = ((const float4*)(yo + (size_t)(TOK + s0) * DD))[d];
  const float4 r1 = ((const float4*)(yo + (size_t)(TOK + s1) * DD))[d];
  float4 r;
  r.x = a.x + w0 * r0.x + w1 * r1.x;
  r.y = a.y + w0 * r0.y + w1 * r1.y;
  r.z = a.z + w0 * r0.z + w1 * r1.z;
  r.w = a.w + w0 * r0.w + w1 * r1.w;
  ((float4*)(out + (size_t)t * DD))[d] = r;
}

// ---------------- launch ----------------
extern "C" void kernel_launch(void* const* d_in, const int* in_sizes, int n_in,
                              void* d_out, int out_size, void* d_ws, size_t ws_size,
                              hipStream_t stream) {
  const float* x   = (const float*)d_in[0];
  const float* gw  = (const float*)d_in[1];
  const float* gb  = (const float*)d_in[2];
  const float* sw1 = (const float*)d_in[3];
  const float* sb1 = (const float*)d_in[4];
  const float* sw2 = (const float*)d_in[5];
  const float* sb2 = (const float*)d_in[6];
  const float* rw1 = (const float*)d_in[7];
  const float* rb1 = (const float*)d_in[8];
  const float* rw2 = (const float*)d_in[9];
  const float* rb2 = (const float*)d_in[10];
  float* out = (float*)d_out;

  char* p = (char*)d_ws;
  auto alloc = [&](size_t bytes) { char* r = p; p += (bytes + 255) & ~(size_t)255; return r; };
  int*   counts = (int*)alloc(EE * 4);
  int*   eidx   = (int*)alloc((size_t)2 * TOK * 4);
  int*   epos   = (int*)alloc((size_t)2 * TOK * 4);
  float* ew     = (float*)alloc((size_t)2 * TOK * 4);
  int*   s2t    = (int*)alloc((size_t)NSLOT * 4);
  float* swt    = (float*)alloc((size_t)NSLOT * 4);
  int*   t2s    = (int*)alloc((size_t)2 * TOK * 4);
  u16*   xb     = (u16*)alloc((size_t)TOK * DD * 2);
  u16*   xg     = (u16*)alloc((size_t)NSLOT * DD * 2);
  u16*   w1t    = (u16*)alloc((size_t)9 * TWOF * DD * 2);
  u16*   w2t    = (u16*)alloc((size_t)9 * DD * FF * 2);
  u16*   hs     = (u16*)alloc((size_t)(TOK + NSLOT + 256) * FF * 2);
  // yo aliases w1t: gemm2 runs strictly after gemm1 (same stream); ~100.8MB <= 151MB
  float* yo     = (float*)w1t;

  hipMemsetAsync(counts, 0, EE * 4, stream);
  gate_kernel<<<TOK / 4, 256, 0, stream>>>(x, gw, gb, counts, eidx, epos, ew);
  slot_kernel<<<(2 * TOK) / 256, 256, 0, stream>>>(eidx, epos, ew, counts, s2t, swt, t2s);
  cvtx_kernel<<<(TOK * DD / 4) / 256, 256, 0, stream>>>(x, xb);
  gather_kernel<<<(NSLOT * 128) / 256, 256, 0, stream>>>(xb, s2t, xg);
  wt_kernel<<<dim3(TWOF / 32, DD / 32, 9), 256, 0, stream>>>(sw1, rw1, w1t, DD, TWOF, 1);
  wt_kernel<<<dim3(DD / 32, FF / 32, 9), 256, 0, stream>>>(sw2, rw2, w2t, FF, DD, 0);
  gemm1_kernel<<<dim3(TWOF / 256, 64, 9), 512, 0, stream>>>(xb, xg, w1t, sb1, rb1, counts, hs);
  gemm2_kernel<<<dim3(DD / 256, 64, 9), 512, 0, stream>>>(hs, w2t, sb2, rb2, counts, yo);
  combine_kernel<<<TOK, 256, 0, stream>>>(yo, t2s, ew, out);
}

// Round 6
// 1112.336 us; speedup vs baseline: 1.1463x; 1.1463x over previous
//
#include <hip/hip_runtime.h>

#define TOK   8192
#define DD    1024
#define FF    4096
#define EE    8
#define TWOF  8192
#define NSLOT 16384   // TOK * top_k(2)
#define PADT  17408   // NSLOT + 8*128 (per-expert 128-row padding bound)

typedef unsigned short u16;
typedef float  f32x16 __attribute__((ext_vector_type(16)));
typedef __bf16 bf16x8 __attribute__((ext_vector_type(8)));

__device__ __forceinline__ u16 f2b(float f) {
  unsigned u = __builtin_bit_cast(unsigned, f);
  u += 0x7fffu + ((u >> 16) & 1u);   // RNE; inputs finite
  return (u16)(u >> 16);
}

__device__ __forceinline__ void ldslds16(const void* g, void* l) {
  __builtin_amdgcn_global_load_lds((const __attribute__((address_space(1))) void*)g,
                                   (__attribute__((address_space(3))) void*)l, 16, 0, 0);
}

// ---------------- gate: logits, softmax, top-2, counts ----------------
__global__ void gate_kernel(const float* __restrict__ x, const float* __restrict__ gw,
                            const float* __restrict__ gb, int* __restrict__ counts,
                            int* __restrict__ eidx, int* __restrict__ epos,
                            float* __restrict__ ew) {
  const int wave = threadIdx.x >> 6, lane = threadIdx.x & 63;
  const int t = blockIdx.x * 4 + wave;
  float acc[EE] = {0,0,0,0,0,0,0,0};
  const float* xr = x + (size_t)t * DD;
  for (int d = lane; d < DD; d += 64) {
    float xv = xr[d];
    const float* g = gw + (size_t)d * EE;
#pragma unroll
    for (int e = 0; e < EE; ++e) acc[e] += xv * g[e];
  }
#pragma unroll
  for (int e = 0; e < EE; ++e)
#pragma unroll
    for (int off = 32; off > 0; off >>= 1) acc[e] += __shfl_down(acc[e], off);
  if (lane == 0) {
    float l[EE];
#pragma unroll
    for (int e = 0; e < EE; ++e) l[e] = acc[e] + gb[e];
    int i0 = 0;
    for (int e = 1; e < EE; ++e) if (l[e] > l[i0]) i0 = e;
    int i1 = (i0 == 0) ? 1 : 0;
    for (int e = 0; e < EE; ++e) { if (e == i0) continue; if (l[e] > l[i1]) i1 = e; }
    float m = l[0];
    for (int e = 1; e < EE; ++e) m = fmaxf(m, l[e]);
    float s = 0.f, p[EE];
    for (int e = 0; e < EE; ++e) { p[e] = __expf(l[e] - m); s += p[e]; }
    float w0 = p[i0] / s, w1 = p[i1] / s;
    int p0 = atomicAdd(&counts[i0], 1);
    int p1 = atomicAdd(&counts[i1], 1);
    eidx[2*t] = i0; eidx[2*t+1] = i1;
    epos[2*t] = p0; epos[2*t+1] = p1;
    ew[2*t] = w0;  ew[2*t+1] = w1;
  }
}

// setup: meta[0..7]=opad (128-aligned expert slot offsets), meta[8..16]=tm-block prefix
__global__ void setup_kernel(const int* __restrict__ counts, int* __restrict__ meta) {
  if (threadIdx.x == 0 && blockIdx.x == 0) {
    int s = 0, tm = 0;
    for (int e = 0; e < EE; ++e) {
      meta[e] = s;
      meta[8 + e] = tm;
      s  += (counts[e] + 127) & ~127;
      tm += (counts[e] + 127) >> 7;
    }
    meta[16] = tm;
  }
}

// slot: padded slot = opad[e] + epos
__global__ void slot_kernel(const int* __restrict__ eidx, const int* __restrict__ epos,
                            const float* __restrict__ ew, const int* __restrict__ meta,
                            int* __restrict__ s2t, float* __restrict__ swt,
                            int* __restrict__ t2s) {
  int i = blockIdx.x * 256 + threadIdx.x;           // 0..2T-1
  int e = eidx[i];
  int slot = meta[e] + epos[i];
  s2t[slot] = i >> 1;
  swt[slot] = ew[i];
  t2s[i] = slot;
}

// ---------------- conversions ----------------
__global__ void cvtx_kernel(const float* __restrict__ x, u16* __restrict__ xb) {
  int i = blockIdx.x * 256 + threadIdx.x;           // 4 elements each
  float4 v = ((const float4*)x)[i];
  unsigned lo = (unsigned)f2b(v.x) | ((unsigned)f2b(v.y) << 16);
  unsigned hi = (unsigned)f2b(v.z) | ((unsigned)f2b(v.w) << 16);
  ((uint2*)xb)[i] = make_uint2(lo, hi);
}

__global__ void gather_kernel(const u16* __restrict__ xb, const int* __restrict__ s2t,
                              u16* __restrict__ xg) {
  int i = blockIdx.x * 256 + threadIdx.x;           // 16B chunks, PADT rows
  int row = i >> 7, c = i & 127;
  int tok = s2t[row];                                // pad slots are 0 (memset)
  ((int4*)xg)[(size_t)row * 128 + c] = ((const int4*)xb)[(size_t)tok * 128 + c];
}

// transpose-convert weights: dst[seg][n][k] (bf16) = src[seg][k][oc(n)] (f32)
// permute (w1 only): interleave a/b halves in 32-col groups (SwiGLU pairing, 32x32 MFMA)
__global__ void wt_kernel(const float* __restrict__ srcS, const float* __restrict__ srcR,
                          u16* __restrict__ dst, int K, int N, int permute) {
  __shared__ float tile[32][33];
  const int seg = blockIdx.z;
  const float* src = (seg == 0) ? srcS : srcR + (size_t)(seg - 1) * K * N;
  const int pc0 = blockIdx.x * 32, k0 = blockIdx.y * 32;
  const int tid = threadIdx.x;
  {
    int kk = tid >> 3, j4 = (tid & 7) << 2;
    const float* srow = src + (size_t)(k0 + kk) * N;
#pragma unroll
    for (int q = 0; q < 4; ++q) {
      int n = pc0 + j4 + q;
      int oc = permute ? (((n >> 6) << 5) + (n & 31) + ((n & 32) ? FF : 0)) : n;
      tile[kk][j4 + q] = srow[oc];
    }
  }
  __syncthreads();
  {
    int pp = tid >> 3, kq = (tid & 7) << 2;
    u16* drow = dst + (size_t)seg * N * K + (size_t)(pc0 + pp) * K + k0 + kq;
#pragma unroll
    for (int q = 0; q < 4; ++q) drow[q] = f2b(tile[kq + q][pp]);
  }
}

// ================= 128x128x64 GEMM core — 32x32x16 MFMA, hoisted swizzled bases =====
// 4 waves (2Mx2N), per-wave 64x64 out (2x2 frags of 32x32). LDS 32 KiB.
// Swizzle: byte col ^= (row&7)<<4 on 128B rows; pre-swizzled global source + swizzled read.

__device__ __forceinline__ void kloop32(int niter,
    const char* a0, const char* a1, const char* a2, const char* a3,
    const char* b0, const char* b1, const char* b2, const char* b3,
    u16* As, u16* Bs, int tid, f32x16 (&acc)[2][2]) {
  const int lane = tid & 63, l31 = lane & 31, kg = (lane >> 5) * 16;
  const int wid = tid >> 6, wm = wid >> 1, wn = wid & 1;
  const int C = (l31 & 7) << 4;
  const char* rA[4]; const char* rB[4];
#pragma unroll
  for (int ks = 0; ks < 4; ++ks) {        // 4 k-windows of 16 within BK=64
    const int o = (ks * 32 + kg) ^ C;
    rA[ks] = (const char*)As + (wm * 64 + l31) * 128 + o;
    rB[ks] = (const char*)Bs + (wn * 64 + l31) * 128 + o;
  }
  for (int it = 0; it < niter; ++it) {
    const long long kb = (long long)it * 128;        // 64 u16 per iter
    ldslds16(a0 + kb, As + tid * 8);
    ldslds16(a1 + kb, As + 2048 + tid * 8);
    ldslds16(a2 + kb, As + 4096 + tid * 8);
    ldslds16(a3 + kb, As + 6144 + tid * 8);
    ldslds16(b0 + kb, Bs + tid * 8);
    ldslds16(b1 + kb, Bs + 2048 + tid * 8);
    ldslds16(b2 + kb, Bs + 4096 + tid * 8);
    ldslds16(b3 + kb, Bs + 6144 + tid * 8);
    __syncthreads();
#pragma unroll
    for (int ks = 0; ks < 4; ++ks) {
      bf16x8 af0 = *(const bf16x8*)(rA[ks]);
      bf16x8 af1 = *(const bf16x8*)(rA[ks] + 4096);   // +32 rows
      bf16x8 bq0 = *(const bf16x8*)(rB[ks]);
      bf16x8 bq1 = *(const bf16x8*)(rB[ks] + 4096);
      acc[0][0] = __builtin_amdgcn_mfma_f32_32x32x16_bf16(af0, bq0, acc[0][0], 0, 0, 0);
      acc[0][1] = __builtin_amdgcn_mfma_f32_32x32x16_bf16(af0, bq1, acc[0][1], 0, 0, 0);
      acc[1][0] = __builtin_amdgcn_mfma_f32_32x32x16_bf16(af1, bq0, acc[1][0], 0, 0, 0);
      acc[1][1] = __builtin_amdgcn_mfma_f32_32x32x16_bf16(af1, bq1, acc[1][1], 0, 0, 0);
    }
    __syncthreads();
  }
}

// map compact g -> (seg, tm, rowstart, rows) ; returns false if out of range
__device__ __forceinline__ bool seg_map(int g, const int* __restrict__ counts,
                                        const int* __restrict__ meta,
                                        int& seg, int& tm, int& rowstart, int& rows) {
  if (g < 64) { seg = 0; tm = g; rowstart = 0; rows = TOK; return true; }
  int gr = g - 64;
  if (gr >= meta[16]) return false;
  int e = 0;
  while (gr >= meta[8 + e + 1]) ++e;     // gr < meta[16] guarantees termination
  seg = e + 1; tm = gr - meta[8 + e];
  rowstart = meta[e]; rows = counts[e];
  return true;
}

// ---------------- GEMM1: x @ w1t(permuted) -> SwiGLU -> hs bf16 ----------------
__global__ __launch_bounds__(256, 4)
void gemm1_kernel(const u16* __restrict__ xb, const u16* __restrict__ xg,
                  const u16* __restrict__ w1t, const float* __restrict__ sb1,
                  const float* __restrict__ rb1, const int* __restrict__ counts,
                  const int* __restrict__ meta, u16* __restrict__ hs) {
  __shared__ __align__(16) u16 As[128 * 64];
  __shared__ __align__(16) u16 Bs[128 * 64];
  // XCD L2 chunking: same tn -> same lin&7 -> same XCD; B-panel per XCD = 2 MB (L2-fit)
  const int lin = blockIdx.x + 64 * blockIdx.y;
  const int tn = (lin & 7) * 8 + ((lin >> 3) & 7);
  const int g = lin >> 6;
  int seg, tm, rowstart, rows;
  if (!seg_map(g, counts, meta, seg, tm, rowstart, rows)) return;
  const u16* A = (seg == 0) ? xb : xg;
  const int hsbase = (seg == 0) ? 0 : TOK + rowstart;
  const int tid = threadIdx.x, lane = tid & 63, wid = tid >> 6;
  const int wm = wid >> 1, wn = wid & 1;

  const int srow = tid >> 3;
  const int scol = ((tid & 7) * 16) ^ ((srow & 7) << 4);
  const char* Ac = (const char*)A;
  const char* Bc = (const char*)(w1t + (size_t)seg * TWOF * DD);
  const char* a[4]; const char* b[4];
#pragma unroll
  for (int r = 0; r < 4; ++r) {
    int rg = rowstart + tm * 128 + r * 32 + srow;    // padded region allocated
    a[r] = Ac + (size_t)rg * (DD * 2) + scol;
    b[r] = Bc + (size_t)(tn * 128 + r * 32 + srow) * (DD * 2) + scol;
  }

  f32x16 acc[2][2] = {};
  kloop32(DD / 64, a[0], a[1], a[2], a[3], b[0], b[1], b[2], b[3],
          As, Bs, tid, acc);

  const int l31 = lane & 31, lg = lane >> 5;
  const int rlim = rows - tm * 128;
  const float* b1 = (seg == 0) ? sb1 : rb1 + (size_t)(seg - 1) * TWOF;
  const int f = (tn * 2 + wn) * 32 + l31;
  const float ba = b1[f], bb = b1[FF + f];
  u16* hbase = hs + (size_t)(hsbase + tm * 128) * FF;
#pragma unroll
  for (int mi = 0; mi < 2; ++mi)
#pragma unroll
    for (int reg = 0; reg < 16; ++reg) {
      int lr = wm * 64 + mi * 32 + (reg & 3) + 8 * (reg >> 2) + 4 * lg;
      if (lr < rlim) {
        float av = acc[mi][0][reg] + ba;
        float bv = acc[mi][1][reg] + bb;
        float sv = av / (1.0f + __expf(-av)) * bv;
        hbase[(size_t)lr * FF + f] = f2b(sv);
      }
    }
}

// ---------------- GEMM2: hs @ w2t -> yo (f32, all segments, no atomics) ----------------
__global__ __launch_bounds__(256, 4)
void gemm2_kernel(const u16* __restrict__ hs, const u16* __restrict__ w2t,
                  const float* __restrict__ sb2, const float* __restrict__ rb2,
                  const int* __restrict__ counts, const int* __restrict__ meta,
                  float* __restrict__ yo) {
  __shared__ __align__(16) u16 As[128 * 64];
  __shared__ __align__(16) u16 Bs[128 * 64];
  const int tn = blockIdx.x;                         // 8 tn == 8 XCDs naturally
  const int g = blockIdx.y;
  int seg, tm, rowstart, rows;
  if (!seg_map(g, counts, meta, seg, tm, rowstart, rows)) return;
  const int hrow0 = (seg == 0) ? 0 : TOK + rowstart;
  const int tid = threadIdx.x, lane = tid & 63, wid = tid >> 6;
  const int wm = wid >> 1, wn = wid & 1;

  const int srow = tid >> 3;
  const int scol = ((tid & 7) * 16) ^ ((srow & 7) << 4);
  const char* Ac = (const char*)hs;
  const char* Bc = (const char*)(w2t + (size_t)seg * DD * FF);
  const char* a[4]; const char* b[4];
#pragma unroll
  for (int r = 0; r < 4; ++r) {
    a[r] = Ac + (size_t)(hrow0 + tm * 128 + r * 32 + srow) * (FF * 2) + scol;
    b[r] = Bc + (size_t)(tn * 128 + r * 32 + srow) * (FF * 2) + scol;
  }

  f32x16 acc[2][2] = {};
  kloop32(FF / 64, a[0], a[1], a[2], a[3], b[0], b[1], b[2], b[3],
          As, Bs, tid, acc);

  const int l31 = lane & 31, lg = lane >> 5;
  const int rlim = rows - tm * 128;
  const float* b2 = (seg == 0) ? sb2 : rb2 + (size_t)(seg - 1) * DD;
  const int c0 = tn * 128 + wn * 64 + l31;
  const float bias0 = b2[c0], bias1 = b2[c0 + 32];
  float* ybase = yo + (size_t)(hrow0 + tm * 128) * DD;
#pragma unroll
  for (int mi = 0; mi < 2; ++mi)
#pragma unroll
    for (int reg = 0; reg < 16; ++reg) {
      int lr = wm * 64 + mi * 32 + (reg & 3) + 8 * (reg >> 2) + 4 * lg;
      if (lr < rlim) {
        float* orow = ybase + (size_t)lr * DD;
        orow[c0]      = acc[mi][0][reg] + bias0;
        orow[c0 + 32] = acc[mi][1][reg] + bias1;
      }
    }
}

// ---------------- combine: out[t] = yo[t] + w0*yo[T+s0] + w1*yo[T+s1] ----------------
__global__ void combine_kernel(const float* __restrict__ yo, const int* __restrict__ t2s,
                               const float* __restrict__ ew, float* __restrict__ out) {
  const int t = blockIdx.x, d = threadIdx.x;   // 256 threads x 4 floats
  const float4 a  = ((const float4*)(yo + (size_t)t * DD))[d];
  const int s0 = t2s[2*t], s1 = t2s[2*t+1];
  const float w0 = ew[2*t], w1 = ew[2*t+1];
  const float4 r0 = ((const float4*)(yo + (size_t)(TOK + s0) * DD))[d];
  const float4 r1 = ((const float4*)(yo + (size_t)(TOK + s1) * DD))[d];
  float4 r;
  r.x = a.x + w0 * r0.x + w1 * r1.x;
  r.y = a.y + w0 * r0.y + w1 * r1.y;
  r.z = a.z + w0 * r0.z + w1 * r1.z;
  r.w = a.w + w0 * r0.w + w1 * r1.w;
  ((float4*)(out + (size_t)t * DD))[d] = r;
}

// ---------------- launch ----------------
extern "C" void kernel_launch(void* const* d_in, const int* in_sizes, int n_in,
                              void* d_out, int out_size, void* d_ws, size_t ws_size,
                              hipStream_t stream) {
  const float* x   = (const float*)d_in[0];
  const float* gw  = (const float*)d_in[1];
  const float* gb  = (const float*)d_in[2];
  const float* sw1 = (const float*)d_in[3];
  const float* sb1 = (const float*)d_in[4];
  const float* sw2 = (const float*)d_in[5];
  const float* sb2 = (const float*)d_in[6];
  const float* rw1 = (const float*)d_in[7];
  const float* rb1 = (const float*)d_in[8];
  const float* rw2 = (const float*)d_in[9];
  const float* rb2 = (const float*)d_in[10];
  float* out = (float*)d_out;

  char* p = (char*)d_ws;
  auto alloc = [&](size_t bytes) { char* r = p; p += (bytes + 255) & ~(size_t)255; return r; };
  int*   counts = (int*)alloc(EE * 4);
  int*   meta   = (int*)alloc(17 * 4);
  int*   eidx   = (int*)alloc((size_t)2 * TOK * 4);
  int*   epos   = (int*)alloc((size_t)2 * TOK * 4);
  float* ew     = (float*)alloc((size_t)2 * TOK * 4);
  int*   s2t    = (int*)alloc((size_t)PADT * 4);
  float* swt    = (float*)alloc((size_t)PADT * 4);
  int*   t2s    = (int*)alloc((size_t)2 * TOK * 4);
  u16*   xb     = (u16*)alloc((size_t)TOK * DD * 2);
  u16*   xg     = (u16*)alloc((size_t)PADT * DD * 2);
  u16*   w1t    = (u16*)alloc((size_t)9 * TWOF * DD * 2);
  u16*   w2t    = (u16*)alloc((size_t)9 * DD * FF * 2);
  u16*   hs     = (u16*)alloc((size_t)(TOK + PADT + 128) * FF * 2);
  // yo aliases w1t: gemm2 runs strictly after gemm1 (same stream); ~105MB <= 151MB
  float* yo     = (float*)w1t;

  hipMemsetAsync(counts, 0, EE * 4, stream);
  hipMemsetAsync(s2t, 0, (size_t)PADT * 4, stream);
  gate_kernel<<<TOK / 4, 256, 0, stream>>>(x, gw, gb, counts, eidx, epos, ew);
  setup_kernel<<<1, 64, 0, stream>>>(counts, meta);
  slot_kernel<<<(2 * TOK) / 256, 256, 0, stream>>>(eidx, epos, ew, meta, s2t, swt, t2s);
  cvtx_kernel<<<(TOK * DD / 4) / 256, 256, 0, stream>>>(x, xb);
  gather_kernel<<<PADT / 2, 256, 0, stream>>>(xb, s2t, xg);
  wt_kernel<<<dim3(TWOF / 32, DD / 32, 9), 256, 0, stream>>>(sw1, rw1, w1t, DD, TWOF, 1);
  wt_kernel<<<dim3(DD / 32, FF / 32, 9), 256, 0, stream>>>(sw2, rw2, w2t, FF, DD, 0);
  gemm1_kernel<<<dim3(64, 199), 256, 0, stream>>>(xb, xg, w1t, sb1, rb1, counts, meta, hs);
  gemm2_kernel<<<dim3(8, 199), 256, 0, stream>>>(hs, w2t, sb2, rb2, counts, meta, yo);
  combine_kernel<<<TOK, 256, 0, stream>>>(yo, t2s, ew, out);
}